// Round 4
// baseline (214.236 us; speedup 1.0000x reference)
//
#include <hip/hip_runtime.h>

#define NBINS 256
#define BLOCK 256                     // 4 waves/block
#define WAVES (BLOCK / 64)
#define BIN_SCALE (256.0f / 255.0f)   // torch.histc width=(255-0)/256; idx=floor(x/width)
#define GRID 2048                     // 8 blocks/CU * 256 CU -> 32 waves/CU (occupancy cap)
#define RBLOCKS 16                    // reduce: 16 blocks x 16 bins each (64 B slices)

// ---- fallback-only helpers (workspace too small; not expected in practice) ----
__global__ void zero_out(float* __restrict__ out) {
    const int i = blockIdx.x * blockDim.x + threadIdx.x;
    if (i < 2 * NBINS) out[i] = 0.0f;
}
__global__ void count_kernel(const void* __restrict__ bs_raw,
                             float* __restrict__ out) {
    const int as_int = *(const int*)bs_raw;
    float bs = (as_int >= 1 && as_int < (1 << 20)) ? (float)as_int : *(const float*)bs_raw;
    out[NBINS + threadIdx.x] = bs * out[0];
}

// torch.histc semantics: idx = floor(x / ((255-0)/256)); x==255 -> last bin; OOR dropped.
__device__ __forceinline__ void bump(float v, unsigned* __restrict__ hw) {
    int idx = (int)(v * BIN_SCALE);          // trunc == floor for v >= 0
    idx = idx < 255 ? idx : 255;
    if (v >= 0.0f && v <= 255.0f)
        atomicAdd(&hw[idx], 1u);             // ds_add_u32: no return -> no dep chain
}

__global__ __launch_bounds__(BLOCK, 8) void hist_kernel(const float* __restrict__ x,
                                                        unsigned int* __restrict__ partial,
                                                        float* __restrict__ out,
                                                        int n, int G, int use_ws) {
    // Per-wave u32 histograms: 4 KB LDS; ds_add has no RMW dep chain; 8 blocks/CU.
    __shared__ unsigned int h[WAVES][NBINS];
    const int t = threadIdx.x;
    unsigned* __restrict__ hw = h[t >> 6];

#pragma unroll
    for (int i = t; i < WAVES * NBINS; i += BLOCK) ((unsigned*)h)[i] = 0u;
    __syncthreads();

    const int n4 = n >> 2;
    const float4* __restrict__ x4 = (const float4*)x;
    const int S = G * BLOCK;
    const int i0 = blockIdx.x * BLOCK + t;

    // Unroll-4: all four float4 loads issue before any ds_add -> 4 KB in flight
    // per wave; 32 waves/CU of TLP on top. ds_adds are fire-and-forget.
    int i = i0;
    for (; i + 3 * S < n4; i += 4 * S) {
        const float4 a = x4[i];
        const float4 b = x4[i + S];
        const float4 c = x4[i + 2 * S];
        const float4 d = x4[i + 3 * S];
        bump(a.x, hw); bump(a.y, hw); bump(a.z, hw); bump(a.w, hw);
        bump(b.x, hw); bump(b.y, hw); bump(b.z, hw); bump(b.w, hw);
        bump(c.x, hw); bump(c.y, hw); bump(c.z, hw); bump(c.w, hw);
        bump(d.x, hw); bump(d.y, hw); bump(d.z, hw); bump(d.w, hw);
    }
    for (; i < n4; i += S) {
        const float4 a = x4[i];
        bump(a.x, hw); bump(a.y, hw); bump(a.z, hw); bump(a.w, hw);
    }
    // scalar remainder (n % 4)
    for (int j = (n4 << 2) + i0; j < n; j += S)
        bump(x[j], hw);

    __syncthreads();

    // Merge 4 wave-histograms; bank = t&31, conflict-free.
    unsigned s = h[0][t] + h[1][t] + h[2][t] + h[3][t];
    if (use_ws) {
        partial[(size_t)blockIdx.x * NBINS + t] = s;   // coalesced 1 KB store
    } else if (s) {
        atomicAdd(&out[t], (float)s);                  // fallback (needs zero_out)
    }
}

// Fused reduce + count, coalesced: block b owns bins [b*16, b*16+16) — a 64 B
// contiguous slice of each row. Thread (r = t>>4, c = t&15) sums rows
// g = r, r+16, ... : one wave-load touches 4 rows x 64 B = 4 L2 transactions
// (vs 64 for the round-3 column layout). LDS transpose-reduce, direct write,
// no atomics, no pre-zero. Block 0 also writes count = bs * hist[0].
__global__ __launch_bounds__(NBINS) void reduce_count_kernel(const unsigned int* __restrict__ partial,
                                                             const void* __restrict__ bs_raw,
                                                             float* __restrict__ out,
                                                             int G) {
    const int t = threadIdx.x;
    const int c = t & 15;             // bin within this block's group
    const int r = t >> 4;             // row-phase 0..15
    const int bin0 = blockIdx.x * 16;

    unsigned s = 0;
    for (int g = r; g < G; g += 16)
        s += partial[(size_t)g * NBINS + bin0 + c];

    __shared__ unsigned sums[16][17];  // +1 pad
    sums[r][c] = s;
    __syncthreads();

    __shared__ float h0_sh;
    if (t < 16) {
        unsigned total = 0;
#pragma unroll
        for (int rr = 0; rr < 16; ++rr) total += sums[rr][t];
        out[bin0 + t] = (float)total;          // exact: integer counts < 2^24
        if (blockIdx.x == 0 && t == 0) h0_sh = (float)total;   // hist[0]
    }
    if (blockIdx.x == 0) {
        __syncthreads();
        const int as_int = *(const int*)bs_raw;
        float bs = (as_int >= 1 && as_int < (1 << 20)) ? (float)as_int
                                                       : *(const float*)bs_raw;
        out[NBINS + t] = bs * h0_sh;
    }
}

extern "C" void kernel_launch(void* const* d_in, const int* in_sizes, int n_in,
                              void* d_out, int out_size, void* d_ws, size_t ws_size,
                              hipStream_t stream) {
    const void* bs_ptr;
    const float* x;
    int n;
    if (n_in >= 2 && in_sizes[0] == 1) {
        bs_ptr = d_in[0];
        x = (const float*)d_in[1];
        n = in_sizes[1];
    } else {
        bs_ptr = d_in[1];
        x = (const float*)d_in[0];
        n = in_sizes[0];
    }

    float* out = (float*)d_out;                    // [256 hist | 256 count], float32
    unsigned int* partial = (unsigned int*)d_ws;   // [G][256] u32 partials

    const int G = GRID;                            // grid-stride covers any n
    const size_t ws_need = (size_t)G * NBINS * sizeof(unsigned int);   // 2 MB
    const int use_ws = (ws_size >= ws_need) ? 1 : 0;

    if (use_ws) {
        hist_kernel<<<G, BLOCK, 0, stream>>>(x, partial, out, n, G, 1);
        reduce_count_kernel<<<RBLOCKS, NBINS, 0, stream>>>(partial, bs_ptr, out, G);
    } else {
        zero_out<<<2, 256, 0, stream>>>(out);
        hist_kernel<<<G, BLOCK, 0, stream>>>(x, partial, out, n, G, 0);
        count_kernel<<<1, NBINS, 0, stream>>>(bs_ptr, out);
    }
}

// Round 5
// 212.032 us; speedup vs baseline: 1.0104x; 1.0104x over previous
//
#include <hip/hip_runtime.h>

#define NBINS 256
#define BLOCK 256                     // 4 waves/block
#define WAVES (BLOCK / 64)
#define BIN_SCALE (256.0f / 255.0f)   // torch.histc width=(255-0)/256; idx=floor(x/width)
#define GRID 2048                     // 8 blocks/CU * 256 CU -> 32 waves/CU (occupancy cap)
#define RBLOCKS 16                    // reduce: 16 blocks x 16 bins each (64 B slices)

// ---- fallback-only helpers (workspace too small; not expected in practice) ----
__global__ void zero_out(float* __restrict__ out) {
    const int i = blockIdx.x * blockDim.x + threadIdx.x;
    if (i < 2 * NBINS) out[i] = 0.0f;
}
__global__ void count_kernel(const void* __restrict__ bs_raw,
                             float* __restrict__ out) {
    const int as_int = *(const int*)bs_raw;
    float bs = (as_int >= 1 && as_int < (1 << 20)) ? (float)as_int : *(const float*)bs_raw;
    out[NBINS + threadIdx.x] = bs * out[0];
}

// torch.histc semantics: idx = floor(x / ((255-0)/256)); x==255 -> last bin; OOR dropped.
__device__ __forceinline__ void bump(float v, unsigned* __restrict__ hw) {
    int idx = (int)(v * BIN_SCALE);          // trunc == floor for v >= 0
    idx = idx < 255 ? idx : 255;
    if (v >= 0.0f && v <= 255.0f)
        atomicAdd(&hw[idx], 1u);             // ds_add_u32: no return -> no dep chain
}

__global__ __launch_bounds__(BLOCK, 8) void hist_kernel(const float* __restrict__ x,
                                                        unsigned int* __restrict__ partial,
                                                        float* __restrict__ out,
                                                        int n, int G, int use_ws) {
    // Per-wave u32 histograms: 4 KB LDS; ds_add has no RMW dep chain; 8 blocks/CU.
    __shared__ unsigned int h[WAVES][NBINS];
    const int t = threadIdx.x;
    unsigned* __restrict__ hw = h[t >> 6];

#pragma unroll
    for (int i = t; i < WAVES * NBINS; i += BLOCK) ((unsigned*)h)[i] = 0u;
    __syncthreads();

    const int n4 = n >> 2;
    const float4* __restrict__ x4 = (const float4*)x;
    const int S = G * BLOCK;
    const int i0 = blockIdx.x * BLOCK + t;

    // Unroll-2 (proven in rounds 2/3): both float4 loads issue before any ds_add
    // -> 2 KB in flight/wave; 32 waves/CU of TLP hides the rest. Unroll-4 was
    // tried (round 4): -19 us — VGPR pressure under __launch_bounds__(256,8)
    // defeats the extra ILP. Do not deepen.
    int i = i0;
    for (; i + S < n4; i += 2 * S) {
        const float4 a = x4[i];
        const float4 b = x4[i + S];
        bump(a.x, hw); bump(a.y, hw); bump(a.z, hw); bump(a.w, hw);
        bump(b.x, hw); bump(b.y, hw); bump(b.z, hw); bump(b.w, hw);
    }
    if (i < n4) {
        const float4 a = x4[i];
        bump(a.x, hw); bump(a.y, hw); bump(a.z, hw); bump(a.w, hw);
    }
    // scalar remainder (n % 4)
    for (int j = (n4 << 2) + i0; j < n; j += S)
        bump(x[j], hw);

    __syncthreads();

    // Merge 4 wave-histograms; bank = t&31, conflict-free.
    unsigned s = h[0][t] + h[1][t] + h[2][t] + h[3][t];
    if (use_ws) {
        partial[(size_t)blockIdx.x * NBINS + t] = s;   // coalesced 1 KB store
    } else if (s) {
        atomicAdd(&out[t], (float)s);                  // fallback (needs zero_out)
    }
}

// Fused reduce + count, coalesced: block b owns bins [b*16, b*16+16) — a 64 B
// contiguous slice of each row. Thread (r = t>>4, c = t&15) sums rows
// g = r, r+16, ... : one wave-load touches 4 rows x 64 B = 4 L2 transactions
// (vs 64 for the column layout). LDS transpose-reduce, direct write, no
// atomics, no pre-zero. Block 0 also writes count = bs * hist[0].
__global__ __launch_bounds__(NBINS) void reduce_count_kernel(const unsigned int* __restrict__ partial,
                                                             const void* __restrict__ bs_raw,
                                                             float* __restrict__ out,
                                                             int G) {
    const int t = threadIdx.x;
    const int c = t & 15;             // bin within this block's group
    const int r = t >> 4;             // row-phase 0..15
    const int bin0 = blockIdx.x * 16;

    unsigned s = 0;
    for (int g = r; g < G; g += 16)
        s += partial[(size_t)g * NBINS + bin0 + c];

    __shared__ unsigned sums[16][17];  // +1 pad
    sums[r][c] = s;
    __syncthreads();

    __shared__ float h0_sh;
    if (t < 16) {
        unsigned total = 0;
#pragma unroll
        for (int rr = 0; rr < 16; ++rr) total += sums[rr][t];
        out[bin0 + t] = (float)total;          // exact: integer counts < 2^24
        if (blockIdx.x == 0 && t == 0) h0_sh = (float)total;   // hist[0]
    }
    if (blockIdx.x == 0) {
        __syncthreads();
        const int as_int = *(const int*)bs_raw;
        float bs = (as_int >= 1 && as_int < (1 << 20)) ? (float)as_int
                                                       : *(const float*)bs_raw;
        out[NBINS + t] = bs * h0_sh;
    }
}

extern "C" void kernel_launch(void* const* d_in, const int* in_sizes, int n_in,
                              void* d_out, int out_size, void* d_ws, size_t ws_size,
                              hipStream_t stream) {
    const void* bs_ptr;
    const float* x;
    int n;
    if (n_in >= 2 && in_sizes[0] == 1) {
        bs_ptr = d_in[0];
        x = (const float*)d_in[1];
        n = in_sizes[1];
    } else {
        bs_ptr = d_in[1];
        x = (const float*)d_in[0];
        n = in_sizes[0];
    }

    float* out = (float*)d_out;                    // [256 hist | 256 count], float32
    unsigned int* partial = (unsigned int*)d_ws;   // [G][256] u32 partials

    const int G = GRID;                            // grid-stride covers any n
    const size_t ws_need = (size_t)G * NBINS * sizeof(unsigned int);   // 2 MB
    const int use_ws = (ws_size >= ws_need) ? 1 : 0;

    if (use_ws) {
        hist_kernel<<<G, BLOCK, 0, stream>>>(x, partial, out, n, G, 1);
        reduce_count_kernel<<<RBLOCKS, NBINS, 0, stream>>>(partial, bs_ptr, out, G);
    } else {
        zero_out<<<2, 256, 0, stream>>>(out);
        hist_kernel<<<G, BLOCK, 0, stream>>>(x, partial, out, n, G, 0);
        count_kernel<<<1, NBINS, 0, stream>>>(bs_ptr, out);
    }
}